// Round 4
// baseline (589.836 us; speedup 1.0000x reference)
//
#include <hip/hip_runtime.h>
#include <math.h>

// HBV model RHS: elementwise over B=2,000,000 rows.
// Inputs (dict order):
//   d_in[0] = y            (B,5)   float32   in_sizes[0] = 5B
//   d_in[1] = theta        (14,)   float32
//   d_in[2] = climate_data (8,B,3) float32
//   d_in[3] = delta_t      scalar  float32
//   d_in[4] = t            scalar  int32
// Output: concat[ dS (B,5), fluxes (B,12) ] float32, out_size = 17B
//
// R3 scheme (R2 + compile fix): 4 consecutive rows per thread. 4 rows x 5
// floats = 80B = 5x float4 (always 16B-aligned), climate 48B = 3x float4,
// dS 5x float4, fluxes 12x float4. No LDS, no barriers, 4x MLP per thread.
// Outputs are streaming-only -> nontemporal stores (via native ext_vector
// float4, since __builtin_nontemporal_store rejects HIP_vector_type).

#define BLOCK 256

typedef float nfloat4 __attribute__((ext_vector_type(4)));

struct HbvParams {
    float tt, tti, ttm, cfr, cfmax, whc, cflux, fc, lp, beta, k0, alpha, perc, k1, dt;
};

__device__ __forceinline__ void hbv_row(const float S1, const float S2, const float S3,
                                        const float S4, const float S5,
                                        const float P, const float Ep, const float T,
                                        const HbvParams& p,
                                        float* __restrict__ d,   // 5
                                        float* __restrict__ f)   // 12
{
    const float zero = 0.0f;
    const float flux_sf   = fminf(P, fmaxf(zero, P * (p.tt + 0.5f * p.tti - T) / p.tti));
    const float flux_refr = fmaxf(fminf(p.cfr * p.cfmax * (p.ttm - T), S2 / p.dt), zero);
    const float flux_melt = fmaxf(fminf(p.cfmax * (T - p.ttm), S1 / p.dt), zero);
    const float flux_rf   = fminf(P, fmaxf(zero, P * (T - (p.tt - 0.5f * p.tti)) / p.tti));

    const float r = 0.01f, e = 5.0f;
    const float Smax_raw = p.whc * S1;
    const float Smax     = fmaxf(Smax_raw, zero);
    const float logistic = 1.0f / (1.0f + expf((S2 - Smax + r * e * Smax) / fmaxf(r, r * Smax)));
    const float flux_in  = (flux_rf + flux_melt) * (1.0f - logistic);
    const float flux_se  = fmaxf((S2 - Smax_raw) / p.dt, zero);
    const float flux_cf  = fminf(p.cflux * (1.0f - S3 / p.fc), S4 / p.dt);
    const float flux_ea  = fminf(fminf(S3 / (p.lp * p.fc) * Ep, Ep), S3 / p.dt);
    const float flux_r   = (flux_in + flux_se) * powf(fmaxf(S3, zero) / p.fc, p.beta);
    const float flux_q0  = fminf(p.k0 * powf(fmaxf(S4, zero), 1.0f + p.alpha), fmaxf(S4 / p.dt, zero));
    const float flux_perc = fminf(p.perc, S4 / p.dt);
    const float flux_q1  = p.k1 * S5;

    d[0] = flux_sf + flux_refr - flux_melt;
    d[1] = flux_rf + flux_melt - flux_refr - flux_in - flux_se;
    d[2] = flux_in + flux_se + flux_cf - flux_ea - flux_r;
    d[3] = flux_r - flux_cf - flux_q0 - flux_perc;
    d[4] = flux_perc - flux_q1;

    f[0] = flux_sf;  f[1] = flux_refr; f[2] = flux_melt; f[3] = flux_rf;
    f[4] = flux_in;  f[5] = flux_se;   f[6] = flux_cf;   f[7] = flux_ea;
    f[8] = flux_r;   f[9] = flux_q0;   f[10] = flux_perc; f[11] = flux_q1;
}

__global__ __launch_bounds__(BLOCK) void hbv_rhs_kernel(
    const float* __restrict__ y,
    const float* __restrict__ theta,
    const float* __restrict__ climate,
    const float* __restrict__ dt_ptr,
    const int* __restrict__ t_ptr,
    float* __restrict__ dS,
    float* __restrict__ fluxes,
    int B)
{
    const int j = blockIdx.x * blockDim.x + threadIdx.x;   // 4-row group index
    const int r0 = j * 4;
    if (r0 >= B) return;

    HbvParams p;
    p.tt    = theta[0];  p.tti   = theta[1];  p.ttm   = theta[2];
    p.cfr   = theta[3];  p.cfmax = theta[4];  p.whc   = theta[5];
    p.cflux = theta[6];  p.fc    = theta[7];  p.lp    = theta[8];
    p.beta  = theta[9];  p.k0    = theta[10]; p.alpha = theta[11];
    p.perc  = theta[12]; p.k1    = theta[13];
    p.dt    = dt_ptr[0];
    const int t = t_ptr[0];
    const float* __restrict__ ct = climate + (size_t)t * (size_t)B * 3u;

    if (r0 + 3 < B) {
        // ---- fast path: 4 full rows, all float4 ----
        const nfloat4* __restrict__ y4 = (const nfloat4*)(y  + (size_t)j * 20u);
        const nfloat4* __restrict__ c4 = (const nfloat4*)(ct + (size_t)j * 12u);
        nfloat4 a0 = y4[0], a1 = y4[1], a2 = y4[2], a3 = y4[3], a4 = y4[4];
        nfloat4 c0 = c4[0], c1 = c4[1], c2 = c4[2];

        float S[4][5] = {
            { a0.x, a0.y, a0.z, a0.w, a1.x },
            { a1.y, a1.z, a1.w, a2.x, a2.y },
            { a2.z, a2.w, a3.x, a3.y, a3.z },
            { a3.w, a4.x, a4.y, a4.z, a4.w }
        };
        float C[4][3] = {
            { c0.x, c0.y, c0.z },
            { c0.w, c1.x, c1.y },
            { c1.z, c1.w, c2.x },
            { c2.y, c2.z, c2.w }
        };

        float d[4][5], f[4][12];
        #pragma unroll
        for (int k = 0; k < 4; ++k)
            hbv_row(S[k][0], S[k][1], S[k][2], S[k][3], S[k][4],
                    C[k][0], C[k][1], C[k][2], p, d[k], f[k]);

        nfloat4* __restrict__ d4 = (nfloat4*)(dS + (size_t)j * 20u);
        const float* dd = &d[0][0];
        #pragma unroll
        for (int k = 0; k < 5; ++k) {
            nfloat4 v = { dd[4*k], dd[4*k+1], dd[4*k+2], dd[4*k+3] };
            __builtin_nontemporal_store(v, d4 + k);
        }

        nfloat4* __restrict__ f4 = (nfloat4*)(fluxes + (size_t)j * 48u);
        const float* ff = &f[0][0];
        #pragma unroll
        for (int k = 0; k < 12; ++k) {
            nfloat4 v = { ff[4*k], ff[4*k+1], ff[4*k+2], ff[4*k+3] };
            __builtin_nontemporal_store(v, f4 + k);
        }
    } else {
        // ---- tail: per-row scalar ----
        for (int rr = r0; rr < B; ++rr) {
            const size_t yb = (size_t)rr * 5u;
            const size_t cb = (size_t)rr * 3u;
            float d[5], f[12];
            hbv_row(y[yb], y[yb+1], y[yb+2], y[yb+3], y[yb+4],
                    ct[cb], ct[cb+1], ct[cb+2], p, d, f);
            for (int q = 0; q < 5; ++q)  dS[(size_t)rr * 5u + q] = d[q];
            for (int q = 0; q < 12; ++q) fluxes[(size_t)rr * 12u + q] = f[q];
        }
    }
}

extern "C" void kernel_launch(void* const* d_in, const int* in_sizes, int n_in,
                              void* d_out, int out_size, void* d_ws, size_t ws_size,
                              hipStream_t stream) {
    const float* y       = (const float*)d_in[0];
    const float* theta   = (const float*)d_in[1];
    const float* climate = (const float*)d_in[2];
    const float* dt_ptr  = (const float*)d_in[3];
    const int*   t_ptr   = (const int*)d_in[4];

    const int B = in_sizes[0] / 5;

    float* dS     = (float*)d_out;                   // B*5
    float* fluxes = (float*)d_out + (size_t)B * 5u;  // B*12

    const int ngroups = (B + 3) / 4;
    const int grid    = (ngroups + BLOCK - 1) / BLOCK;
    hbv_rhs_kernel<<<grid, BLOCK, 0, stream>>>(y, theta, climate, dt_ptr, t_ptr,
                                               dS, fluxes, B);
}